// Round 11
// baseline (5927.269 us; speedup 1.0000x reference)
//
#include <hip/hip_runtime.h>
#include <cstdint>
#include <cstddef>

typedef __bf16 bf16;
typedef float f32x4 __attribute__((ext_vector_type(4)));
typedef bf16 bf16x8 __attribute__((ext_vector_type(8)));
typedef unsigned u32x4 __attribute__((ext_vector_type(4)));

#define AS1 __attribute__((address_space(1)))
#define AS3 __attribute__((address_space(3)))

__device__ __forceinline__ void gload_lds16(const void* g, void* l) {
  __builtin_amdgcn_global_load_lds((AS1 void*)g, (AS3 void*)l, 16, 0, 0);
}

#define FLAG_WORDS 1024

// ---------------- init: combined biases + flags ----------------
__global__ __launch_bounds__(256) void init_misc(
    const float* __restrict__ bih0, const float* __restrict__ bhh0,
    const float* __restrict__ bih1, const float* __restrict__ bhh1,
    float* __restrict__ bsum0, float* __restrict__ bsum1, unsigned* __restrict__ flags) {
  int i = blockIdx.x * 256 + threadIdx.x;
  if (i < 4096) {
    bsum0[i] = bih0[i] + bhh0[i];
    bsum1[i] = bih1[i] + bhh1[i];
  }
  if (i < FLAG_WORDS) flags[i] = 0u;
}

// ------- fused embed + GEMM0 (blocks 0..2047) + Wout f32->bf16 (blocks 2048..6047) -------
__global__ __launch_bounds__(256) void gemm_emb(
    const int* __restrict__ x, const float* __restrict__ emb,
    const float* __restrict__ Wih0, const float* __restrict__ bsum0,
    float* __restrict__ C, const float* __restrict__ Wout, bf16* __restrict__ woutb) {
  if (blockIdx.x >= 2048) {
    // Wout conversion: 4000 blocks x 8192 elems
    size_t base = ((size_t)(blockIdx.x - 2048) * 8192) + (size_t)threadIdx.x * 8;
    if (woutb) {
      for (int it = 0; it < 4; ++it) {
        size_t i = base + (size_t)it * 2048;
        f32x4 v0 = *(const f32x4*)(Wout + i);
        f32x4 v1 = *(const f32x4*)(Wout + i + 4);
        bf16x8 r;
        for (int j = 0; j < 4; ++j) { r[j] = (bf16)v0[j]; r[j + 4] = (bf16)v1[j]; }
        *(bf16x8*)(woutb + i) = r;
      }
    }
    return;
  }
  __shared__ bf16 aL[2][4096];
  __shared__ bf16 bL[2][4096];
  const int tid = threadIdx.x;
  const int l = tid & 63, w = tid >> 6;
  const int bm = blockIdx.x & 63;  // 64 row tiles (M=8192)
  const int bn = blockIdx.x >> 6;  // 32 col tiles (N=4096)
  const int wr = (w >> 1) << 6, wc = (w & 1) << 6;
  const int r16 = l & 15, kq = l >> 4;

  f32x4 acc[4][4];
  for (int m = 0; m < 4; ++m)
    for (int n = 0; n < 4; ++n) acc[m][n] = (f32x4){0.f, 0.f, 0.f, 0.f};

  auto stage = [&](int kt, int buf) {
    for (int i = 0; i < 2; ++i) {
      int lin = tid + (i << 8);
      int r = lin >> 2, c = lin & 3;
      int rg = (bm << 7) + r;
      int tok = x[((rg & 15) << 9) + (rg >> 4)];  // x[b*512 + t]
      const float* sa = emb + ((size_t)tok << 10) + (kt << 5) + (c << 3);
      f32x4 a0 = *(const f32x4*)sa;
      f32x4 a1 = *(const f32x4*)(sa + 4);
      bf16x8 oa;
      for (int j = 0; j < 4; ++j) { oa[j] = (bf16)a0[j]; oa[j + 4] = (bf16)a1[j]; }
      *(bf16x8*)&aL[buf][(r << 5) + ((c ^ (r & 3)) << 3)] = oa;
      const float* sb = Wih0 + (size_t)((bn << 7) + r) * 1024 + (kt << 5) + (c << 3);
      f32x4 b0 = *(const f32x4*)sb;
      f32x4 b1 = *(const f32x4*)(sb + 4);
      bf16x8 ob;
      for (int j = 0; j < 4; ++j) { ob[j] = (bf16)b0[j]; ob[j + 4] = (bf16)b1[j]; }
      *(bf16x8*)&bL[buf][(r << 5) + ((c ^ (r & 3)) << 3)] = ob;
    }
  };
  stage(0, 0);
  __syncthreads();
  for (int kt = 0; kt < 32; ++kt) {
    int cur = kt & 1;
    if (kt + 1 < 32) stage(kt + 1, cur ^ 1);
    bf16x8 af[4], bfr[4];
    for (int m = 0; m < 4; ++m) {
      int row = wr + (m << 4) + r16;
      int ch = kq ^ (row & 3);
      af[m] = *(const bf16x8*)&aL[cur][(row << 5) + (ch << 3)];
    }
    for (int n = 0; n < 4; ++n) {
      int row = wc + (n << 4) + r16;
      int ch = kq ^ (row & 3);
      bfr[n] = *(const bf16x8*)&bL[cur][(row << 5) + (ch << 3)];
    }
    for (int m = 0; m < 4; ++m)
      for (int n = 0; n < 4; ++n)
        acc[m][n] = __builtin_amdgcn_mfma_f32_16x16x32_bf16(af[m], bfr[n], acc[m][n], 0, 0, 0);
    __syncthreads();
  }
  float bvv[4];
  for (int n = 0; n < 4; ++n) bvv[n] = bsum0[(bn << 7) + wc + (n << 4) + r16];
  for (int m = 0; m < 4; ++m) {
    int Rbase = (bm << 7) + wr + (m << 4) + (kq << 2);
    for (int r = 0; r < 4; ++r) {
      int R = Rbase + r;
      size_t rowoff = (size_t)R * 4096;
      for (int n = 0; n < 4; ++n)
        C[rowoff + (bn << 7) + wc + (n << 4) + r16] = acc[m][n][r] + bvv[n];
    }
  }
}

// ---------------- projection GEMM (r10, proven): logits = hs1rm @ Wout^T + bout ----------------
template <bool BF16B>
__global__ __launch_bounds__(256) void gemm_proj(
    const bf16* __restrict__ A, const void* __restrict__ Bw_,
    const float* __restrict__ bias, float* __restrict__ C) {
  __shared__ bf16 aL[2][4096];
  __shared__ bf16 bL[2][4096];
  const int tid = threadIdx.x;
  const int l = tid & 63, w = tid >> 6;
  const int k = blockIdx.x % 80, sq = blockIdx.x / 80;
  const int bm = ((sq & 7) << 3) + (k & 7);
  const int bn = (sq >> 3) * 10 + (k >> 3);
  const int wr = (w >> 1) << 6, wc = (w & 1) << 6;
  const int r16 = l & 15, kq = l >> 4;
  const bf16* Bb = (const bf16*)Bw_;
  const float* Bf32 = (const float*)Bw_;

  f32x4 acc[4][4];
  for (int m = 0; m < 4; ++m)
    for (int n = 0; n < 4; ++n) acc[m][n] = (f32x4){0.f, 0.f, 0.f, 0.f};

  auto stageA = [&](int kt, int buf) {
    for (int i = 0; i < 2; ++i) {
      int lin = tid + (i << 8);
      int r = lin >> 2, s = lin & 3, c = s ^ (r & 3);
      gload_lds16(A + (size_t)((bm << 7) + r) * 1024 + (kt << 5) + (c << 3),
                  &aL[buf][lin << 3]);
    }
  };
  stageA(0, 0);
  if (BF16B) {
    for (int i = 0; i < 2; ++i) {
      int lin = tid + (i << 8);
      int r = lin >> 2, s = lin & 3, c = s ^ (r & 3);
      gload_lds16(Bb + (size_t)((bn << 7) + r) * 1024 + (c << 3), &bL[0][lin << 3]);
    }
  } else {
    for (int i = 0; i < 2; ++i) {
      int lin = tid + (i << 8);
      int r = lin >> 2, c = lin & 3;
      const float* src = Bf32 + (size_t)((bn << 7) + r) * 1024 + (c << 3);
      f32x4 v0 = *(const f32x4*)src;
      f32x4 v1 = *(const f32x4*)(src + 4);
      bf16x8 o;
      for (int j = 0; j < 4; ++j) { o[j] = (bf16)v0[j]; o[j + 4] = (bf16)v1[j]; }
      *(bf16x8*)&bL[0][(r << 5) + ((c ^ (r & 3)) << 3)] = o;
    }
  }
  __syncthreads();

  for (int kt = 0; kt < 32; ++kt) {
    const int cur = kt & 1;
    const bool pf = (kt + 1 < 32);
    f32x4 bv0[2], bv1[2];
    int br_[2], bs_[2];
    if (pf) {
      stageA(kt + 1, cur ^ 1);
      if (BF16B) {
        for (int i = 0; i < 2; ++i) {
          int lin = tid + (i << 8);
          int r = lin >> 2, s = lin & 3, c = s ^ (r & 3);
          gload_lds16(Bb + (size_t)((bn << 7) + r) * 1024 + ((kt + 1) << 5) + (c << 3),
                      &bL[cur ^ 1][lin << 3]);
        }
      } else {
        for (int i = 0; i < 2; ++i) {
          int lin = tid + (i << 8);
          int r = lin >> 2, c = lin & 3;
          const float* src = Bf32 + (size_t)((bn << 7) + r) * 1024 + ((kt + 1) << 5) + (c << 3);
          bv0[i] = *(const f32x4*)src;
          bv1[i] = *(const f32x4*)(src + 4);
          br_[i] = r;
          bs_[i] = c ^ (r & 3);
        }
      }
    }
    bf16x8 af[4], bfr[4];
    for (int m = 0; m < 4; ++m) {
      int row = wr + (m << 4) + r16;
      int ch = kq ^ (row & 3);
      af[m] = *(const bf16x8*)&aL[cur][(row << 5) + (ch << 3)];
    }
    for (int n = 0; n < 4; ++n) {
      int row = wc + (n << 4) + r16;
      int ch = kq ^ (row & 3);
      bfr[n] = *(const bf16x8*)&bL[cur][(row << 5) + (ch << 3)];
    }
    for (int m = 0; m < 4; ++m)
      for (int n = 0; n < 4; ++n)
        acc[m][n] = __builtin_amdgcn_mfma_f32_16x16x32_bf16(af[m], bfr[n], acc[m][n], 0, 0, 0);
    if (pf && !BF16B) {
      for (int i = 0; i < 2; ++i) {
        bf16x8 o;
        for (int j = 0; j < 4; ++j) { o[j] = (bf16)bv0[i][j]; o[j + 4] = (bf16)bv1[i][j]; }
        *(bf16x8*)&bL[cur ^ 1][(br_[i] << 5) + (bs_[i] << 3)] = o;
      }
    }
    __syncthreads();
  }

  float bvv[4];
  for (int n = 0; n < 4; ++n) bvv[n] = bias[(bn << 7) + wc + (n << 4) + r16];
  for (int m = 0; m < 4; ++m) {
    int Rbase = (bm << 7) + wr + (m << 4) + (kq << 2);
    for (int r = 0; r < 4; ++r) {
      int R = Rbase + r;
      int tt = R >> 4, bb = R & 15;
      size_t rowoff = ((size_t)bb * 512 + tt) * 32000;
      for (int n = 0; n < 4; ++n) {
        float v = acc[m][n][r] + bvv[n];
        float* cp = &C[rowoff + (bn << 7) + wc + (n << 4) + r16];
        asm volatile("global_store_dword %0, %1, off nt" ::"v"(cp), "v"(v) : "memory");
      }
    }
  }
}

// ---------------- wave-granular 3-group persistent LSTM (row-major planes) ----------------
// bid 0..63 L0 | 64..127 B (gx1[t]=Wih1*h0[t]+bsum1, full 512-slot, feed-forward)
// | 128..191 L1. h planes row-major [16 b][1024 cols] (2KB rows, 32KB/step);
// consumer fragment = ONE contiguous dwordx4; 32 fragments preloaded to regs.
// hs1 plane == hs1rm (projection input) -> no mirror store.
__global__ __launch_bounds__(256, 1) void lstm_pipe4(
    const float* __restrict__ gx,     // [T*16][4096]
    const float* __restrict__ Whh0,   // [4096][1024] f32
    const float* __restrict__ Wih1,   // [4096][1024] f32
    const float* __restrict__ Whh1,   // [4096][1024] f32
    const float* __restrict__ bsum1,  // [4096]
    bf16* __restrict__ hs0b,          // [T][16][1024] planes
    bf16* __restrict__ hs1rm,         // [T][16][1024] planes == row-major proj input
    float* __restrict__ gx1,          // [T][65536] f32 (written once per slot)
    unsigned* __restrict__ flags,     // FLAG_WORDS, zeroed
    int T) {
  __shared__ bf16 wlds[4][16 * 1024];   // 128 KB weights
  __shared__ unsigned short hb[4][64];  // per-wave transpose bounce
  __shared__ unsigned tokv[4];
  const int tid = threadIdx.x;
  const int l = tid & 63, w = tid >> 6;
  const int bid = blockIdx.x;
  const int r16 = l & 15, kq = l >> 4;
  unsigned* const fL0 = flags;         // [256] per-wave epochs
  unsigned* const fB = flags + 256;    // [256]
  unsigned* const fL1 = flags + 512;   // [256]
  const int typ = bid >> 6;  // 0=L0, 1=B, 2=L1
  const int lb = bid & 63;
  const int widx = lb * 4 + w;
  const int colbase = lb * 16 + w * 4;

  {
    const float* Wsrc = (typ == 0) ? Whh0 : ((typ == 1) ? Wih1 : Whh1);
    for (int it = 0; it < 32; ++it) {
      int lin = it * 64 + l;
      int row = lin >> 7, cs = lin & 127, c = cs ^ (row & 7);
      const float* s = Wsrc + (size_t)((row >> 2) * 1024 + colbase + (row & 3)) * 1024 + c * 8;
      f32x4 v0 = *(const f32x4*)s;
      f32x4 v1 = *(const f32x4*)(s + 4);
      bf16x8 o;
      for (int j = 0; j < 4; ++j) { o[j] = (bf16)v0[j]; o[j + 4] = (bf16)v1[j]; }
      *(bf16x8*)&wlds[w][row * 1024 + cs * 8] = o;
    }
  }
  if (tid < 4) tokv[tid] = 0;
  __syncthreads();

  const int gcol = (r16 >> 2) * 1024 + colbase + (r16 & 3);
  const int b0s = (r16 >> 2) & 1, b1s = (r16 >> 3) & 1;
  const int rx = r16 & 7;

  // wait for all 256 waves of a group: lane l polls word l of its wave's quarter
  auto pollq = [&](unsigned* arr, unsigned tgt) {
    unsigned* q = arr + (w << 6) + l;
    for (;;) {
      unsigned a = __hip_atomic_load(q, __ATOMIC_RELAXED, __HIP_MEMORY_SCOPE_AGENT);
      if (__all(a >= tgt)) break;
      __builtin_amdgcn_s_sleep(2);
    }
    volatile unsigned* tk = tokv;
    if (l == 0) tk[w] = tgt;
    while (tk[0] < tgt || tk[1] < tgt || tk[2] < tgt || tk[3] < tgt) {
    }
    asm volatile("" ::: "memory");
  };
  auto poll1 = [&](unsigned* p, unsigned tgt) {
    while (__hip_atomic_load(p, __ATOMIC_RELAXED, __HIP_MEMORY_SCOPE_AGENT) < tgt)
      __builtin_amdgcn_s_sleep(2);
    asm volatile("" ::: "memory");
  };
  // MFMA chain over row-major plane: preload 32 contiguous dwordx4 fragments
  auto chain = [&](const bf16* plane) -> f32x4 {
    const char* hp = (const char*)plane + r16 * 2048 + kq * 16;
    u32x4 fr[32];
#pragma unroll
    for (int kk = 0; kk < 32; ++kk) fr[kk] = *(const u32x4*)(hp + kk * 64);
    f32x4 a0 = (f32x4){0.f, 0.f, 0.f, 0.f};
    f32x4 a1 = (f32x4){0.f, 0.f, 0.f, 0.f};
#pragma unroll
    for (int kk = 0; kk < 32; kk += 2) {
      bf16x8 A0 = __builtin_bit_cast(bf16x8, fr[kk]);
      bf16x8 A1 = __builtin_bit_cast(bf16x8, fr[kk + 1]);
      bf16x8 B0 = *(const bf16x8*)&wlds[w][r16 * 1024 + (((kk * 4 + kq) ^ rx) << 3)];
      bf16x8 B1 = *(const bf16x8*)&wlds[w][r16 * 1024 + ((((kk + 1) * 4 + kq) ^ rx) << 3)];
      a0 = __builtin_amdgcn_mfma_f32_16x16x32_bf16(A0, B0, a0, 0, 0, 0);
      a1 = __builtin_amdgcn_mfma_f32_16x16x32_bf16(A1, B1, a1, 0, 0, 0);
    }
    return a0 + a1;
  };
  auto gates = [&](f32x4 acc, float* cst, float* hv) {
    for (int r = 0; r < 4; ++r) {
      float own = acc[r];
      float p4 = __shfl_xor(own, 4, 64);
      float ev = b0s ? p4 : own;
      float ov = b0s ? own : p4;
      float ev8 = __shfl_xor(ev, 8, 64);
      float ov8 = __shfl_xor(ov, 8, 64);
      float xi = b1s ? ev8 : ev;
      float xf = b1s ? ov8 : ov;
      float xg = b1s ? ev : ev8;
      float xo = b1s ? ov : ov8;
      float ig = 1.f / (1.f + __expf(-xi));
      float fg = 1.f / (1.f + __expf(-xf));
      float eg = __expf(2.f * xg);
      float gv = 1.f - 2.f / (eg + 1.f);
      float og = 1.f / (1.f + __expf(-xo));
      cst[r] = fg * cst[r] + ig * gv;
      float ec = __expf(2.f * cst[r]);
      float th = 1.f - 2.f / (ec + 1.f);
      hv[r] = og * th;
    }
  };
  // transpose [col][b] -> [b][4 cols] via LDS bounce, then 16 scattered 8B sc1 stores
  auto hstore = [&](float* hv, char* plane) {
    if (r16 < 4) {
      volatile unsigned short* hbp = hb[w];
      for (int r = 0; r < 4; ++r) {
        bf16 hbv = (bf16)hv[r];
        hbp[(kq * 4 + r) * 4 + r16] = __builtin_bit_cast(unsigned short, hbv);
      }
    }
    if (l < 16) {
      unsigned long long rowv = *(volatile unsigned long long*)&hb[w][l * 4];
      char* dst = plane + l * 2048 + widx * 8;
      asm volatile("global_store_dwordx2 %0, %1, off sc1" ::"v"(dst), "v"(rowv) : "memory");
    }
  };

  if (typ == 1) {  // ---------- B: gx1[t] = Wih1*h0[t] + bsum1 (feed-forward) ----------
    const float bsv = bsum1[gcol];
    unsigned* const myflag = fB + widx;
    for (int t = 0; t < T; ++t) {
      pollq(fL0, (unsigned)(t + 1));
      f32x4 acc = chain(hs0b + (size_t)t * 16384);
      for (int r = 0; r < 4; ++r) acc[r] += bsv;
      float* dst = gx1 + (size_t)t * 65536 + widx * 256 + r16 * 16 + kq * 4;
      asm volatile("global_store_dwordx4 %0, %1, off sc1" ::"v"(dst), "v"(acc) : "memory");
      asm volatile("s_waitcnt vmcnt(0)" ::: "memory");
      if (l == 0)
        __hip_atomic_store(myflag, (unsigned)(t + 1), __ATOMIC_RELAXED, __HIP_MEMORY_SCOPE_AGENT);
    }
    return;
  }

  float cst[4] = {0.f, 0.f, 0.f, 0.f};
  unsigned* const myflag = (typ == 0) ? (fL0 + widx) : (fL1 + widx);
  unsigned* const bpartner = fB + widx;
  bf16* const houts = (typ == 0) ? hs0b : hs1rm;

  for (int t = 0; t < T; ++t) {
    f32x4 acc;
    if (typ == 0) {
      float gxv[4];
      for (int r = 0; r < 4; ++r)  // prefetch before the wait
        gxv[r] = gx[(size_t)(t * 16 + kq * 4 + r) * 4096 + gcol];
      if (t > 0) pollq(fL0, (unsigned)t);
      acc = (f32x4){0.f, 0.f, 0.f, 0.f};
      if (t > 0) acc = chain(houts + (size_t)(t - 1) * 16384);
      for (int r = 0; r < 4; ++r) acc[r] += gxv[r];
    } else {
      poll1(bpartner, (unsigned)(t + 1));  // gx1[t] ready (write-once -> plain load ok)
      if (t > 0) pollq(fL1, (unsigned)t);
      f32x4 g1 = *(const f32x4*)(gx1 + (size_t)t * 65536 + widx * 256 + r16 * 16 + kq * 4);
      acc = (f32x4){0.f, 0.f, 0.f, 0.f};
      if (t > 0) acc = chain(houts + (size_t)(t - 1) * 16384);
      for (int r = 0; r < 4; ++r) acc[r] += g1[r];
    }
    float hv[4];
    gates(acc, cst, hv);
    hstore(hv, (char*)houts + (size_t)t * 32768);
    asm volatile("s_waitcnt vmcnt(0)" ::: "memory");
    if (l == 0)
      __hip_atomic_store(myflag, (unsigned)(t + 1), __ATOMIC_RELAXED, __HIP_MEMORY_SCOPE_AGENT);
  }
}

extern "C" void kernel_launch(void* const* d_in, const int* in_sizes, int n_in,
                              void* d_out, int out_size, void* d_ws, size_t ws_size,
                              hipStream_t stream) {
  const int* x = (const int*)d_in[0];
  const float* emb = (const float*)d_in[1];
  const float* Wih0 = (const float*)d_in[2];
  const float* Whh0 = (const float*)d_in[3];
  const float* bih0 = (const float*)d_in[4];
  const float* bhh0 = (const float*)d_in[5];
  const float* Wih1 = (const float*)d_in[6];
  const float* Whh1 = (const float*)d_in[7];
  const float* bih1 = (const float*)d_in[8];
  const float* bhh1 = (const float*)d_in[9];
  const float* Wout = (const float*)d_in[10];
  const float* bout = (const float*)d_in[11];

  const int T = 512, M = 8192;
  const size_t bfb = (size_t)M * 1024 * 2;              // 16 MiB bf16 plane set
  const size_t out_bytes = (size_t)out_size * 4;        // 1.05 GB
  const size_t woutb_bytes = (size_t)32000 * 1024 * 2;  // 65.5 MB

  char* p = (char*)d_ws;
  bf16* hs1rm = (bf16*)p;         p += bfb;   // hs1 planes == projection input
  float* bsum0 = (float*)p;       p += 4096 * 4;
  float* bsum1 = (float*)p;       p += 4096 * 4;
  unsigned* flags = (unsigned*)p; p += FLAG_WORDS * 4;
  size_t base_need = (size_t)(p - (char*)d_ws);
  const bool fat = ws_size >= base_need + woutb_bytes + 256;
  bf16* woutb = fat ? (bf16*)p : nullptr;

  // d_out scratch (dead until projection writes it):
  float* gx = (float*)d_out;                             // 134 MB @ head
  float* gx1 = (float*)((char*)d_out + (512ull << 20));  // 134 MB full (write-once slots)
  bf16* hs0b = (bf16*)((char*)d_out + out_bytes - bfb);  // 16 MB tail

  init_misc<<<64, 256, 0, stream>>>(bih0, bhh0, bih1, bhh1, bsum0, bsum1, flags);
  gemm_emb<<<2048 + 4000, 256, 0, stream>>>(x, emb, Wih0, bsum0, gx, Wout, woutb);
  lstm_pipe4<<<192, 256, 0, stream>>>(gx, Whh0, Wih1, Whh1, bsum1, hs0b, hs1rm, gx1,
                                      flags, T);
  if (fat)
    gemm_proj<true><<<16000, 256, 0, stream>>>(hs1rm, woutb, bout, (float*)d_out);
  else
    gemm_proj<false><<<16000, 256, 0, stream>>>(hs1rm, Wout, bout, (float*)d_out);
}

// Round 12
// 5306.202 us; speedup vs baseline: 1.1170x; 1.1170x over previous
//
#include <hip/hip_runtime.h>
#include <cstdint>
#include <cstddef>

typedef __bf16 bf16;
typedef float f32x4 __attribute__((ext_vector_type(4)));
typedef bf16 bf16x8 __attribute__((ext_vector_type(8)));

#define AS1 __attribute__((address_space(1)))
#define AS3 __attribute__((address_space(3)))

__device__ __forceinline__ void gload_lds16(const void* g, void* l) {
  __builtin_amdgcn_global_load_lds((AS1 void*)g, (AS3 void*)l, 16, 0, 0);
}

#define FLAG_WORDS 1024

// ---------------- init: combined biases + flags ----------------
__global__ __launch_bounds__(256) void init_misc(
    const float* __restrict__ bih0, const float* __restrict__ bhh0,
    const float* __restrict__ bih1, const float* __restrict__ bhh1,
    float* __restrict__ bsum0, float* __restrict__ bsum1, unsigned* __restrict__ flags) {
  int i = blockIdx.x * 256 + threadIdx.x;
  if (i < 4096) {
    bsum0[i] = bih0[i] + bhh0[i];
    bsum1[i] = bih1[i] + bhh1[i];
  }
  if (i < FLAG_WORDS) flags[i] = 0u;
}

// ------- fused embed + GEMM0 (blocks 0..2047) + Wout f32->bf16 (blocks 2048..6047) -------
__global__ __launch_bounds__(256) void gemm_emb(
    const int* __restrict__ x, const float* __restrict__ emb,
    const float* __restrict__ Wih0, const float* __restrict__ bsum0,
    float* __restrict__ C, const float* __restrict__ Wout, bf16* __restrict__ woutb) {
  if (blockIdx.x >= 2048) {
    size_t base = ((size_t)(blockIdx.x - 2048) * 8192) + (size_t)threadIdx.x * 8;
    if (woutb) {
      for (int it = 0; it < 4; ++it) {
        size_t i = base + (size_t)it * 2048;
        f32x4 v0 = *(const f32x4*)(Wout + i);
        f32x4 v1 = *(const f32x4*)(Wout + i + 4);
        bf16x8 r;
        for (int j = 0; j < 4; ++j) { r[j] = (bf16)v0[j]; r[j + 4] = (bf16)v1[j]; }
        *(bf16x8*)(woutb + i) = r;
      }
    }
    return;
  }
  __shared__ bf16 aL[2][4096];
  __shared__ bf16 bL[2][4096];
  const int tid = threadIdx.x;
  const int l = tid & 63, w = tid >> 6;
  const int bm = blockIdx.x & 63;
  const int bn = blockIdx.x >> 6;
  const int wr = (w >> 1) << 6, wc = (w & 1) << 6;
  const int r16 = l & 15, kq = l >> 4;

  f32x4 acc[4][4];
  for (int m = 0; m < 4; ++m)
    for (int n = 0; n < 4; ++n) acc[m][n] = (f32x4){0.f, 0.f, 0.f, 0.f};

  auto stage = [&](int kt, int buf) {
    for (int i = 0; i < 2; ++i) {
      int lin = tid + (i << 8);
      int r = lin >> 2, c = lin & 3;
      int rg = (bm << 7) + r;
      int tok = x[((rg & 15) << 9) + (rg >> 4)];  // x[b*512 + t]
      const float* sa = emb + ((size_t)tok << 10) + (kt << 5) + (c << 3);
      f32x4 a0 = *(const f32x4*)sa;
      f32x4 a1 = *(const f32x4*)(sa + 4);
      bf16x8 oa;
      for (int j = 0; j < 4; ++j) { oa[j] = (bf16)a0[j]; oa[j + 4] = (bf16)a1[j]; }
      *(bf16x8*)&aL[buf][(r << 5) + ((c ^ (r & 3)) << 3)] = oa;
      const float* sb = Wih0 + (size_t)((bn << 7) + r) * 1024 + (kt << 5) + (c << 3);
      f32x4 b0 = *(const f32x4*)sb;
      f32x4 b1 = *(const f32x4*)(sb + 4);
      bf16x8 ob;
      for (int j = 0; j < 4; ++j) { ob[j] = (bf16)b0[j]; ob[j + 4] = (bf16)b1[j]; }
      *(bf16x8*)&bL[buf][(r << 5) + ((c ^ (r & 3)) << 3)] = ob;
    }
  };
  stage(0, 0);
  __syncthreads();
  for (int kt = 0; kt < 32; ++kt) {
    int cur = kt & 1;
    if (kt + 1 < 32) stage(kt + 1, cur ^ 1);
    bf16x8 af[4], bfr[4];
    for (int m = 0; m < 4; ++m) {
      int row = wr + (m << 4) + r16;
      int ch = kq ^ (row & 3);
      af[m] = *(const bf16x8*)&aL[cur][(row << 5) + (ch << 3)];
    }
    for (int n = 0; n < 4; ++n) {
      int row = wc + (n << 4) + r16;
      int ch = kq ^ (row & 3);
      bfr[n] = *(const bf16x8*)&bL[cur][(row << 5) + (ch << 3)];
    }
    for (int m = 0; m < 4; ++m)
      for (int n = 0; n < 4; ++n)
        acc[m][n] = __builtin_amdgcn_mfma_f32_16x16x32_bf16(af[m], bfr[n], acc[m][n], 0, 0, 0);
    __syncthreads();
  }
  float bvv[4];
  for (int n = 0; n < 4; ++n) bvv[n] = bsum0[(bn << 7) + wc + (n << 4) + r16];
  for (int m = 0; m < 4; ++m) {
    int Rbase = (bm << 7) + wr + (m << 4) + (kq << 2);
    for (int r = 0; r < 4; ++r) {
      int R = Rbase + r;
      size_t rowoff = (size_t)R * 4096;
      for (int n = 0; n < 4; ++n)
        C[rowoff + (bn << 7) + wc + (n << 4) + r16] = acc[m][n][r] + bvv[n];
    }
  }
}

// ---------------- projection GEMM (r10, proven): logits = hs1rm @ Wout^T + bout ----------------
template <bool BF16B>
__global__ __launch_bounds__(256) void gemm_proj(
    const bf16* __restrict__ A, const void* __restrict__ Bw_,
    const float* __restrict__ bias, float* __restrict__ C) {
  __shared__ bf16 aL[2][4096];
  __shared__ bf16 bL[2][4096];
  const int tid = threadIdx.x;
  const int l = tid & 63, w = tid >> 6;
  const int k = blockIdx.x % 80, sq = blockIdx.x / 80;
  const int bm = ((sq & 7) << 3) + (k & 7);
  const int bn = (sq >> 3) * 10 + (k >> 3);
  const int wr = (w >> 1) << 6, wc = (w & 1) << 6;
  const int r16 = l & 15, kq = l >> 4;
  const bf16* Bb = (const bf16*)Bw_;
  const float* Bf32 = (const float*)Bw_;

  f32x4 acc[4][4];
  for (int m = 0; m < 4; ++m)
    for (int n = 0; n < 4; ++n) acc[m][n] = (f32x4){0.f, 0.f, 0.f, 0.f};

  auto stageA = [&](int kt, int buf) {
    for (int i = 0; i < 2; ++i) {
      int lin = tid + (i << 8);
      int r = lin >> 2, s = lin & 3, c = s ^ (r & 3);
      gload_lds16(A + (size_t)((bm << 7) + r) * 1024 + (kt << 5) + (c << 3),
                  &aL[buf][lin << 3]);
    }
  };
  stageA(0, 0);
  if (BF16B) {
    for (int i = 0; i < 2; ++i) {
      int lin = tid + (i << 8);
      int r = lin >> 2, s = lin & 3, c = s ^ (r & 3);
      gload_lds16(Bb + (size_t)((bn << 7) + r) * 1024 + (c << 3), &bL[0][lin << 3]);
    }
  } else {
    for (int i = 0; i < 2; ++i) {
      int lin = tid + (i << 8);
      int r = lin >> 2, c = lin & 3;
      const float* src = Bf32 + (size_t)((bn << 7) + r) * 1024 + (c << 3);
      f32x4 v0 = *(const f32x4*)src;
      f32x4 v1 = *(const f32x4*)(src + 4);
      bf16x8 o;
      for (int j = 0; j < 4; ++j) { o[j] = (bf16)v0[j]; o[j + 4] = (bf16)v1[j]; }
      *(bf16x8*)&bL[0][(r << 5) + ((c ^ (r & 3)) << 3)] = o;
    }
  }
  __syncthreads();

  for (int kt = 0; kt < 32; ++kt) {
    const int cur = kt & 1;
    const bool pf = (kt + 1 < 32);
    f32x4 bv0[2], bv1[2];
    int br_[2], bs_[2];
    if (pf) {
      stageA(kt + 1, cur ^ 1);
      if (BF16B) {
        for (int i = 0; i < 2; ++i) {
          int lin = tid + (i << 8);
          int r = lin >> 2, s = lin & 3, c = s ^ (r & 3);
          gload_lds16(Bb + (size_t)((bn << 7) + r) * 1024 + ((kt + 1) << 5) + (c << 3),
                      &bL[cur ^ 1][lin << 3]);
        }
      } else {
        for (int i = 0; i < 2; ++i) {
          int lin = tid + (i << 8);
          int r = lin >> 2, c = lin & 3;
          const float* src = Bf32 + (size_t)((bn << 7) + r) * 1024 + ((kt + 1) << 5) + (c << 3);
          bv0[i] = *(const f32x4*)src;
          bv1[i] = *(const f32x4*)(src + 4);
          br_[i] = r;
          bs_[i] = c ^ (r & 3);
        }
      }
    }
    bf16x8 af[4], bfr[4];
    for (int m = 0; m < 4; ++m) {
      int row = wr + (m << 4) + r16;
      int ch = kq ^ (row & 3);
      af[m] = *(const bf16x8*)&aL[cur][(row << 5) + (ch << 3)];
    }
    for (int n = 0; n < 4; ++n) {
      int row = wc + (n << 4) + r16;
      int ch = kq ^ (row & 3);
      bfr[n] = *(const bf16x8*)&bL[cur][(row << 5) + (ch << 3)];
    }
    for (int m = 0; m < 4; ++m)
      for (int n = 0; n < 4; ++n)
        acc[m][n] = __builtin_amdgcn_mfma_f32_16x16x32_bf16(af[m], bfr[n], acc[m][n], 0, 0, 0);
    if (pf && !BF16B) {
      for (int i = 0; i < 2; ++i) {
        bf16x8 o;
        for (int j = 0; j < 4; ++j) { o[j] = (bf16)bv0[i][j]; o[j + 4] = (bf16)bv1[i][j]; }
        *(bf16x8*)&bL[cur ^ 1][(br_[i] << 5) + (bs_[i] << 3)] = o;
      }
    }
    __syncthreads();
  }

  float bvv[4];
  for (int n = 0; n < 4; ++n) bvv[n] = bias[(bn << 7) + wc + (n << 4) + r16];
  for (int m = 0; m < 4; ++m) {
    int Rbase = (bm << 7) + wr + (m << 4) + (kq << 2);
    for (int r = 0; r < 4; ++r) {
      int R = Rbase + r;
      int tt = R >> 4, bb = R & 15;
      size_t rowoff = ((size_t)bb * 512 + tt) * 32000;
      for (int n = 0; n < 4; ++n) {
        float v = acc[m][n][r] + bvv[n];
        float* cp = &C[rowoff + (bn << 7) + wc + (n << 4) + r16];
        asm volatile("global_store_dword %0, %1, off nt" ::"v"(cp), "v"(v) : "memory");
      }
    }
  }
}

// ---------------- wave-granular 3-group persistent LSTM (r7 structure, proven) ----------------
// Deltas vs r7: gx1 un-ringed (full 512 slots, B feed-forward, no backpressure poll);
// L1 issues gx1 load before the MFMA chain (latency hidden under chain), waits after.
__global__ __launch_bounds__(256, 1) void lstm_pipe3(
    const float* __restrict__ gx,     // [T*16][4096]
    const float* __restrict__ Whh0,   // [4096][1024] f32
    const float* __restrict__ Wih1,   // [4096][1024] f32
    const float* __restrict__ Whh1,   // [4096][1024] f32
    const float* __restrict__ bsum1,  // [4096]
    bf16* __restrict__ hs0t,          // [T][16384] tile format
    bf16* __restrict__ hs1t,          // [T][16384] tile format
    float* __restrict__ gx1,          // [T][65536] f32 (write-once slots)
    bf16* __restrict__ hs1rm,         // [T*16][1024] row-major (projection input)
    unsigned* __restrict__ flags,     // FLAG_WORDS, zeroed
    int T) {
  __shared__ bf16 wlds[4][16 * 1024];
  __shared__ unsigned short hb[4][64];
  __shared__ unsigned tokv[4];
  const int tid = threadIdx.x;
  const int l = tid & 63, w = tid >> 6;
  const int bid = blockIdx.x;
  const int r16 = l & 15, kq = l >> 4;
  unsigned* const fL0 = flags;
  unsigned* const fB = flags + 256;
  unsigned* const fL1 = flags + 512;
  const int typ = bid >> 6;  // 0=L0, 1=B, 2=L1
  const int lb = bid & 63;
  const int widx = lb * 4 + w;
  const int colbase = lb * 16 + w * 4;

  {
    const float* Wsrc = (typ == 0) ? Whh0 : ((typ == 1) ? Wih1 : Whh1);
    for (int it = 0; it < 32; ++it) {
      int lin = it * 64 + l;
      int row = lin >> 7, cs = lin & 127, c = cs ^ (row & 7);
      const float* s = Wsrc + (size_t)((row >> 2) * 1024 + colbase + (row & 3)) * 1024 + c * 8;
      f32x4 v0 = *(const f32x4*)s;
      f32x4 v1 = *(const f32x4*)(s + 4);
      bf16x8 o;
      for (int j = 0; j < 4; ++j) { o[j] = (bf16)v0[j]; o[j + 4] = (bf16)v1[j]; }
      *(bf16x8*)&wlds[w][row * 1024 + cs * 8] = o;
    }
  }
  if (tid < 4) tokv[tid] = 0;
  __syncthreads();

  const int gcol = (r16 >> 2) * 1024 + colbase + (r16 & 3);
  const int b0s = (r16 >> 2) & 1, b1s = (r16 >> 3) & 1;

  auto pollq = [&](unsigned* arr, unsigned tgt) {
    unsigned* q = arr + w * 64 + (l & 15) * 4;
    for (;;) {
      unsigned a0 = __hip_atomic_load(q + 0, __ATOMIC_RELAXED, __HIP_MEMORY_SCOPE_AGENT);
      unsigned a1 = __hip_atomic_load(q + 1, __ATOMIC_RELAXED, __HIP_MEMORY_SCOPE_AGENT);
      unsigned a2 = __hip_atomic_load(q + 2, __ATOMIC_RELAXED, __HIP_MEMORY_SCOPE_AGENT);
      unsigned a3 = __hip_atomic_load(q + 3, __ATOMIC_RELAXED, __HIP_MEMORY_SCOPE_AGENT);
      if (__all(a0 >= tgt && a1 >= tgt && a2 >= tgt && a3 >= tgt)) break;
      __builtin_amdgcn_s_sleep(2);
    }
    volatile unsigned* tk = tokv;
    if (l == 0) tk[w] = tgt;
    while (tk[0] < tgt || tk[1] < tgt || tk[2] < tgt || tk[3] < tgt) {
    }
    asm volatile("" ::: "memory");
  };
  auto poll1 = [&](unsigned* p, unsigned tgt) {
    while (__hip_atomic_load(p, __ATOMIC_RELAXED, __HIP_MEMORY_SCOPE_AGENT) < tgt)
      __builtin_amdgcn_s_sleep(2);
    asm volatile("" ::: "memory");
  };
  auto chain = [&](const bf16* plane) -> f32x4 {
    f32x4 acc = (f32x4){0.f, 0.f, 0.f, 0.f};
    const char* hp = (const char*)plane;
#pragma unroll 8
    for (int kk = 0; kk < 32; ++kk) {
      int tl = kk * 8 + kq * 2;
      unsigned long long lo = *(const unsigned long long*)(hp + tl * 128 + r16 * 8);
      unsigned long long hi = *(const unsigned long long*)(hp + tl * 128 + 128 + r16 * 8);
      union { struct { unsigned long long a, b; } u; bf16x8 v; } A;
      A.u.a = lo;
      A.u.b = hi;
      bf16x8 Bf = *(const bf16x8*)&wlds[w][r16 * 1024 + (((kk * 4 + kq) ^ (r16 & 7)) << 3)];
      acc = __builtin_amdgcn_mfma_f32_16x16x32_bf16(A.v, Bf, acc, 0, 0, 0);
    }
    return acc;
  };

  if (typ == 1) {  // ---------- B: gx1[t] = Wih1*h0[t] + bsum1 (feed-forward) ----------
    const float bsv = bsum1[gcol];
    unsigned* const myflag = fB + widx;
    for (int t = 0; t < T; ++t) {
      pollq(fL0, (unsigned)(t + 1));
      f32x4 acc = chain(hs0t + (size_t)t * 16384);
      for (int r = 0; r < 4; ++r) acc[r] += bsv;
      float* dst = gx1 + (size_t)t * 65536 + widx * 256 + r16 * 16 + kq * 4;
      asm volatile("global_store_dwordx4 %0, %1, off sc0 sc1" ::"v"(dst), "v"(acc) : "memory");
      asm volatile("s_waitcnt vmcnt(0)" ::: "memory");
      if (l == 0)
        __hip_atomic_store(myflag, (unsigned)(t + 1), __ATOMIC_RELAXED, __HIP_MEMORY_SCOPE_AGENT);
    }
    return;
  }

  float cst[4] = {0.f, 0.f, 0.f, 0.f};
  unsigned* const myflag = (typ == 0) ? (fL0 + widx) : (fL1 + widx);
  unsigned* const bpartner = fB + widx;
  bf16* const houts = (typ == 0) ? hs0t : hs1t;

  for (int t = 0; t < T; ++t) {
    f32x4 acc = (f32x4){0.f, 0.f, 0.f, 0.f};
    f32x4 g1;
    if (typ == 0) {
      float gxv[4];
      for (int r = 0; r < 4; ++r)  // prefetch before the wait
        gxv[r] = gx[(size_t)(t * 16 + kq * 4 + r) * 4096 + gcol];
      if (t > 0) pollq(fL0, (unsigned)t);
      if (t > 0) acc = chain(houts + (size_t)(t - 1) * 16384);
      for (int r = 0; r < 4; ++r) acc[r] += gxv[r];
    } else {
      poll1(bpartner, (unsigned)(t + 1));  // gx1[t] ready
      // issue gx1 load now; completion hidden under the MFMA chain
      const float* gp = gx1 + (size_t)t * 65536 + widx * 256 + r16 * 16 + kq * 4;
      asm volatile("global_load_dwordx4 %0, %1, off sc0 sc1" : "=v"(g1) : "v"(gp) : "memory");
      if (t > 0) pollq(fL1, (unsigned)t);
      if (t > 0) acc = chain(houts + (size_t)(t - 1) * 16384);
      asm volatile("s_waitcnt vmcnt(0)" ::: "memory");
      __builtin_amdgcn_sched_barrier(0);
      for (int r = 0; r < 4; ++r) acc[r] += g1[r];
    }
    float hv[4];
    for (int r = 0; r < 4; ++r) {
      float own = acc[r];
      float p4 = __shfl_xor(own, 4, 64);
      float ev = b0s ? p4 : own;
      float ov = b0s ? own : p4;
      float ev8 = __shfl_xor(ev, 8, 64);
      float ov8 = __shfl_xor(ov, 8, 64);
      float xi = b1s ? ev8 : ev;
      float xf = b1s ? ov8 : ov;
      float xg = b1s ? ev : ev8;
      float xo = b1s ? ov : ov8;
      float ig = 1.f / (1.f + __expf(-xi));
      float fg = 1.f / (1.f + __expf(-xf));
      float eg = __expf(2.f * xg);
      float gv = 1.f - 2.f / (eg + 1.f);
      float og = 1.f / (1.f + __expf(-xo));
      cst[r] = fg * cst[r] + ig * gv;
      float ec = __expf(2.f * cst[r]);
      float th = 1.f - 2.f / (ec + 1.f);
      hv[r] = og * th;
    }
    if (r16 < 4) {
      volatile unsigned short* hbp = hb[w];
      for (int r = 0; r < 4; ++r) {
        bf16 hbv = (bf16)hv[r];
        hbp[(kq * 4 + r) * 4 + r16] = __builtin_bit_cast(unsigned short, hbv);
      }
    }
    unsigned long long rowv = 0;
    if (l < 16) rowv = *(volatile unsigned long long*)&hb[w][l * 4];
    if (l < 16) {
      char* dst = (char*)houts + (size_t)t * 32768 + widx * 128 + l * 8;
      asm volatile("global_store_dwordx2 %0, %1, off sc0 sc1" ::"v"(dst), "v"(rowv) : "memory");
    }
    asm volatile("s_waitcnt vmcnt(0)" ::: "memory");
    if (l == 0)
      __hip_atomic_store(myflag, (unsigned)(t + 1), __ATOMIC_RELAXED, __HIP_MEMORY_SCOPE_AGENT);
    if (typ == 2 && l < 16) {  // projection mirror: off critical path, plain store
      *(unsigned long long*)((char*)hs1rm + ((size_t)(t * 16 + l) * 1024 + colbase) * 2) = rowv;
    }
  }
}

extern "C" void kernel_launch(void* const* d_in, const int* in_sizes, int n_in,
                              void* d_out, int out_size, void* d_ws, size_t ws_size,
                              hipStream_t stream) {
  const int* x = (const int*)d_in[0];
  const float* emb = (const float*)d_in[1];
  const float* Wih0 = (const float*)d_in[2];
  const float* Whh0 = (const float*)d_in[3];
  const float* bih0 = (const float*)d_in[4];
  const float* bhh0 = (const float*)d_in[5];
  const float* Wih1 = (const float*)d_in[6];
  const float* Whh1 = (const float*)d_in[7];
  const float* bih1 = (const float*)d_in[8];
  const float* bhh1 = (const float*)d_in[9];
  const float* Wout = (const float*)d_in[10];
  const float* bout = (const float*)d_in[11];

  const int T = 512, M = 8192;
  const size_t bfb = (size_t)M * 1024 * 2;              // 16 MiB bf16 plane set
  const size_t out_bytes = (size_t)out_size * 4;        // 1.05 GB
  const size_t woutb_bytes = (size_t)32000 * 1024 * 2;  // 65.5 MB

  char* p = (char*)d_ws;
  bf16* hs1rm = (bf16*)p;         p += bfb;
  float* bsum0 = (float*)p;       p += 4096 * 4;
  float* bsum1 = (float*)p;       p += 4096 * 4;
  unsigned* flags = (unsigned*)p; p += FLAG_WORDS * 4;
  size_t base_need = (size_t)(p - (char*)d_ws);
  const bool fat = ws_size >= base_need + woutb_bytes + 256;
  bf16* woutb = fat ? (bf16*)p : nullptr;

  // d_out scratch (dead until projection writes it):
  float* gx = (float*)d_out;                             // 134 MB @ head
  float* gx1 = (float*)((char*)d_out + (512ull << 20));  // 134 MB full (write-once slots)
  char* tail = (char*)d_out + out_bytes - 2 * bfb;       // 32 MB tail
  bf16* hs0t = (bf16*)tail;
  bf16* hs1t = (bf16*)(tail + bfb);

  init_misc<<<64, 256, 0, stream>>>(bih0, bhh0, bih1, bhh1, bsum0, bsum1, flags);
  gemm_emb<<<2048 + 4000, 256, 0, stream>>>(x, emb, Wih0, bsum0, gx, Wout, woutb);
  lstm_pipe3<<<192, 256, 0, stream>>>(gx, Whh0, Wih1, Whh1, bsum1, hs0t, hs1t, gx1, hs1rm,
                                      flags, T);
  if (fat)
    gemm_proj<true><<<16000, 256, 0, stream>>>(hs1rm, woutb, bout, (float*)d_out);
  else
    gemm_proj<false><<<16000, 256, 0, stream>>>(hs1rm, Wout, bout, (float*)d_out);
}

// Round 13
// 4998.803 us; speedup vs baseline: 1.1857x; 1.0615x over previous
//
#include <hip/hip_runtime.h>
#include <cstdint>
#include <cstddef>

typedef __bf16 bf16;
typedef float f32x4 __attribute__((ext_vector_type(4)));
typedef bf16 bf16x8 __attribute__((ext_vector_type(8)));

#define AS1 __attribute__((address_space(1)))
#define AS3 __attribute__((address_space(3)))

__device__ __forceinline__ void gload_lds16(const void* g, void* l) {
  __builtin_amdgcn_global_load_lds((AS1 void*)g, (AS3 void*)l, 16, 0, 0);
}

#define RING 8
#define FLAG_WORDS 1024

// ---------------- init: combined biases + flags ----------------
__global__ __launch_bounds__(256) void init_misc(
    const float* __restrict__ bih0, const float* __restrict__ bhh0,
    const float* __restrict__ bih1, const float* __restrict__ bhh1,
    float* __restrict__ bsum0, float* __restrict__ bsum1, unsigned* __restrict__ flags) {
  int i = blockIdx.x * 256 + threadIdx.x;
  if (i < 4096) {
    bsum0[i] = bih0[i] + bhh0[i];
    bsum1[i] = bih1[i] + bhh1[i];
  }
  if (i < FLAG_WORDS) flags[i] = 0u;
}

// ------- fused embed + GEMM0 (blocks 0..2047) + Wout f32->bf16 (blocks 2048..6047) -------
__global__ __launch_bounds__(256) void gemm_emb(
    const int* __restrict__ x, const float* __restrict__ emb,
    const float* __restrict__ Wih0, const float* __restrict__ bsum0,
    float* __restrict__ C, const float* __restrict__ Wout, bf16* __restrict__ woutb) {
  if (blockIdx.x >= 2048) {
    size_t base = ((size_t)(blockIdx.x - 2048) * 8192) + (size_t)threadIdx.x * 8;
    if (woutb) {
      for (int it = 0; it < 4; ++it) {
        size_t i = base + (size_t)it * 2048;
        f32x4 v0 = *(const f32x4*)(Wout + i);
        f32x4 v1 = *(const f32x4*)(Wout + i + 4);
        bf16x8 r;
        for (int j = 0; j < 4; ++j) { r[j] = (bf16)v0[j]; r[j + 4] = (bf16)v1[j]; }
        *(bf16x8*)(woutb + i) = r;
      }
    }
    return;
  }
  __shared__ bf16 aL[2][4096];
  __shared__ bf16 bL[2][4096];
  const int tid = threadIdx.x;
  const int l = tid & 63, w = tid >> 6;
  const int bm = blockIdx.x & 63;
  const int bn = blockIdx.x >> 6;
  const int wr = (w >> 1) << 6, wc = (w & 1) << 6;
  const int r16 = l & 15, kq = l >> 4;

  // kt-invariant staging params (token ids hoisted out of the k loop)
  const float* embrow[2];
  const float* wrow[2];
  int sdst[2];
  for (int i = 0; i < 2; ++i) {
    int lin = tid + (i << 8);
    int r = lin >> 2, c = lin & 3;
    int rg = (bm << 7) + r;
    int tok = x[((rg & 15) << 9) + (rg >> 4)];  // x[b*512 + t]
    embrow[i] = emb + ((size_t)tok << 10) + (c << 3);
    wrow[i] = Wih0 + (size_t)((bn << 7) + r) * 1024 + (c << 3);
    sdst[i] = (r << 5) + ((c ^ (r & 3)) << 3);
  }

  f32x4 acc[4][4];
  for (int m = 0; m < 4; ++m)
    for (int n = 0; n < 4; ++n) acc[m][n] = (f32x4){0.f, 0.f, 0.f, 0.f};

  auto stage = [&](int kt, int buf) {
    for (int i = 0; i < 2; ++i) {
      const float* sa = embrow[i] + (kt << 5);
      f32x4 a0 = *(const f32x4*)sa;
      f32x4 a1 = *(const f32x4*)(sa + 4);
      bf16x8 oa;
      for (int j = 0; j < 4; ++j) { oa[j] = (bf16)a0[j]; oa[j + 4] = (bf16)a1[j]; }
      *(bf16x8*)&aL[buf][sdst[i]] = oa;
      const float* sb = wrow[i] + (kt << 5);
      f32x4 b0 = *(const f32x4*)sb;
      f32x4 b1 = *(const f32x4*)(sb + 4);
      bf16x8 ob;
      for (int j = 0; j < 4; ++j) { ob[j] = (bf16)b0[j]; ob[j + 4] = (bf16)b1[j]; }
      *(bf16x8*)&bL[buf][sdst[i]] = ob;
    }
  };
  stage(0, 0);
  __syncthreads();
  for (int kt = 0; kt < 32; ++kt) {
    int cur = kt & 1;
    if (kt + 1 < 32) stage(kt + 1, cur ^ 1);
    bf16x8 af[4], bfr[4];
    for (int m = 0; m < 4; ++m) {
      int row = wr + (m << 4) + r16;
      int ch = kq ^ (row & 3);
      af[m] = *(const bf16x8*)&aL[cur][(row << 5) + (ch << 3)];
    }
    for (int n = 0; n < 4; ++n) {
      int row = wc + (n << 4) + r16;
      int ch = kq ^ (row & 3);
      bfr[n] = *(const bf16x8*)&bL[cur][(row << 5) + (ch << 3)];
    }
    for (int m = 0; m < 4; ++m)
      for (int n = 0; n < 4; ++n)
        acc[m][n] = __builtin_amdgcn_mfma_f32_16x16x32_bf16(af[m], bfr[n], acc[m][n], 0, 0, 0);
    __syncthreads();
  }
  float bvv[4];
  for (int n = 0; n < 4; ++n) bvv[n] = bsum0[(bn << 7) + wc + (n << 4) + r16];
  for (int m = 0; m < 4; ++m) {
    int Rbase = (bm << 7) + wr + (m << 4) + (kq << 2);
    for (int r = 0; r < 4; ++r) {
      int R = Rbase + r;
      size_t rowoff = (size_t)R * 4096;
      for (int n = 0; n < 4; ++n)
        C[rowoff + (bn << 7) + wc + (n << 4) + r16] = acc[m][n][r] + bvv[n];
    }
  }
}

// ---------------- projection GEMM (r10, proven): logits = hs1rm @ Wout^T + bout ----------------
template <bool BF16B>
__global__ __launch_bounds__(256) void gemm_proj(
    const bf16* __restrict__ A, const void* __restrict__ Bw_,
    const float* __restrict__ bias, float* __restrict__ C) {
  __shared__ bf16 aL[2][4096];
  __shared__ bf16 bL[2][4096];
  const int tid = threadIdx.x;
  const int l = tid & 63, w = tid >> 6;
  const int k = blockIdx.x % 80, sq = blockIdx.x / 80;
  const int bm = ((sq & 7) << 3) + (k & 7);
  const int bn = (sq >> 3) * 10 + (k >> 3);
  const int wr = (w >> 1) << 6, wc = (w & 1) << 6;
  const int r16 = l & 15, kq = l >> 4;
  const bf16* Bb = (const bf16*)Bw_;
  const float* Bf32 = (const float*)Bw_;

  f32x4 acc[4][4];
  for (int m = 0; m < 4; ++m)
    for (int n = 0; n < 4; ++n) acc[m][n] = (f32x4){0.f, 0.f, 0.f, 0.f};

  auto stageA = [&](int kt, int buf) {
    for (int i = 0; i < 2; ++i) {
      int lin = tid + (i << 8);
      int r = lin >> 2, s = lin & 3, c = s ^ (r & 3);
      gload_lds16(A + (size_t)((bm << 7) + r) * 1024 + (kt << 5) + (c << 3),
                  &aL[buf][lin << 3]);
    }
  };
  stageA(0, 0);
  if (BF16B) {
    for (int i = 0; i < 2; ++i) {
      int lin = tid + (i << 8);
      int r = lin >> 2, s = lin & 3, c = s ^ (r & 3);
      gload_lds16(Bb + (size_t)((bn << 7) + r) * 1024 + (c << 3), &bL[0][lin << 3]);
    }
  } else {
    for (int i = 0; i < 2; ++i) {
      int lin = tid + (i << 8);
      int r = lin >> 2, c = lin & 3;
      const float* src = Bf32 + (size_t)((bn << 7) + r) * 1024 + (c << 3);
      f32x4 v0 = *(const f32x4*)src;
      f32x4 v1 = *(const f32x4*)(src + 4);
      bf16x8 o;
      for (int j = 0; j < 4; ++j) { o[j] = (bf16)v0[j]; o[j + 4] = (bf16)v1[j]; }
      *(bf16x8*)&bL[0][(r << 5) + ((c ^ (r & 3)) << 3)] = o;
    }
  }
  __syncthreads();

  for (int kt = 0; kt < 32; ++kt) {
    const int cur = kt & 1;
    const bool pf = (kt + 1 < 32);
    f32x4 bv0[2], bv1[2];
    int br_[2], bs_[2];
    if (pf) {
      stageA(kt + 1, cur ^ 1);
      if (BF16B) {
        for (int i = 0; i < 2; ++i) {
          int lin = tid + (i << 8);
          int r = lin >> 2, s = lin & 3, c = s ^ (r & 3);
          gload_lds16(Bb + (size_t)((bn << 7) + r) * 1024 + ((kt + 1) << 5) + (c << 3),
                      &bL[cur ^ 1][lin << 3]);
        }
      } else {
        for (int i = 0; i < 2; ++i) {
          int lin = tid + (i << 8);
          int r = lin >> 2, c = lin & 3;
          const float* src = Bf32 + (size_t)((bn << 7) + r) * 1024 + ((kt + 1) << 5) + (c << 3);
          bv0[i] = *(const f32x4*)src;
          bv1[i] = *(const f32x4*)(src + 4);
          br_[i] = r;
          bs_[i] = c ^ (r & 3);
        }
      }
    }
    bf16x8 af[4], bfr[4];
    for (int m = 0; m < 4; ++m) {
      int row = wr + (m << 4) + r16;
      int ch = kq ^ (row & 3);
      af[m] = *(const bf16x8*)&aL[cur][(row << 5) + (ch << 3)];
    }
    for (int n = 0; n < 4; ++n) {
      int row = wc + (n << 4) + r16;
      int ch = kq ^ (row & 3);
      bfr[n] = *(const bf16x8*)&bL[cur][(row << 5) + (ch << 3)];
    }
    for (int m = 0; m < 4; ++m)
      for (int n = 0; n < 4; ++n)
        acc[m][n] = __builtin_amdgcn_mfma_f32_16x16x32_bf16(af[m], bfr[n], acc[m][n], 0, 0, 0);
    if (pf && !BF16B) {
      for (int i = 0; i < 2; ++i) {
        bf16x8 o;
        for (int j = 0; j < 4; ++j) { o[j] = (bf16)bv0[i][j]; o[j + 4] = (bf16)bv1[i][j]; }
        *(bf16x8*)&bL[cur ^ 1][(br_[i] << 5) + (bs_[i] << 3)] = o;
      }
    }
    __syncthreads();
  }

  float bvv[4];
  for (int n = 0; n < 4; ++n) bvv[n] = bias[(bn << 7) + wc + (n << 4) + r16];
  for (int m = 0; m < 4; ++m) {
    int Rbase = (bm << 7) + wr + (m << 4) + (kq << 2);
    for (int r = 0; r < 4; ++r) {
      int R = Rbase + r;
      int tt = R >> 4, bb = R & 15;
      size_t rowoff = ((size_t)bb * 512 + tt) * 32000;
      for (int n = 0; n < 4; ++n) {
        float v = acc[m][n][r] + bvv[n];
        float* cp = &C[rowoff + (bn << 7) + wc + (n << 4) + r16];
        asm volatile("global_store_dword %0, %1, off nt" ::"v"(cp), "v"(v) : "memory");
      }
    }
  }
}

// ---------------- wave-granular 3-group persistent LSTM pipeline (r10-exact, proven) ----------------
__global__ __launch_bounds__(256, 1) void lstm_pipe3(
    const float* __restrict__ gx,     // [T*16][4096]
    const float* __restrict__ Whh0,   // [4096][1024] f32
    const float* __restrict__ Wih1,   // [4096][1024] f32
    const float* __restrict__ Whh1,   // [4096][1024] f32
    const float* __restrict__ bsum1,  // [4096]
    bf16* __restrict__ hs0t,          // [T][16384] tile format
    bf16* __restrict__ hs1t,          // [T][16384] tile format
    float* __restrict__ gx1,          // ring [8][65536] f32
    bf16* __restrict__ hs1rm,         // [T*16][1024] row-major (projection input)
    unsigned* __restrict__ flags,     // FLAG_WORDS, zeroed
    int T) {
  __shared__ bf16 wlds[4][16 * 1024];
  __shared__ unsigned short hb[4][64];
  __shared__ unsigned tokv[4];
  const int tid = threadIdx.x;
  const int l = tid & 63, w = tid >> 6;
  const int bid = blockIdx.x;
  const int r16 = l & 15, kq = l >> 4;
  unsigned* const fL0 = flags;
  unsigned* const fB = flags + 256;
  unsigned* const fL1 = flags + 512;
  const int typ = bid >> 6;  // 0=L0, 1=B, 2=L1
  const int lb = bid & 63;
  const int widx = lb * 4 + w;
  const int colbase = lb * 16 + w * 4;

  {
    const float* Wsrc = (typ == 0) ? Whh0 : ((typ == 1) ? Wih1 : Whh1);
    for (int it = 0; it < 32; ++it) {
      int lin = it * 64 + l;
      int row = lin >> 7, cs = lin & 127, c = cs ^ (row & 7);
      const float* s = Wsrc + (size_t)((row >> 2) * 1024 + colbase + (row & 3)) * 1024 + c * 8;
      f32x4 v0 = *(const f32x4*)s;
      f32x4 v1 = *(const f32x4*)(s + 4);
      bf16x8 o;
      for (int j = 0; j < 4; ++j) { o[j] = (bf16)v0[j]; o[j + 4] = (bf16)v1[j]; }
      *(bf16x8*)&wlds[w][row * 1024 + cs * 8] = o;
    }
  }
  if (tid < 4) tokv[tid] = 0;
  __syncthreads();

  const int gcol = (r16 >> 2) * 1024 + colbase + (r16 & 3);
  const int b0s = (r16 >> 2) & 1, b1s = (r16 >> 3) & 1;

  auto pollq = [&](unsigned* arr, unsigned tgt) {
    unsigned* q = arr + w * 64 + (l & 15) * 4;
    for (;;) {
      unsigned a0 = __hip_atomic_load(q + 0, __ATOMIC_RELAXED, __HIP_MEMORY_SCOPE_AGENT);
      unsigned a1 = __hip_atomic_load(q + 1, __ATOMIC_RELAXED, __HIP_MEMORY_SCOPE_AGENT);
      unsigned a2 = __hip_atomic_load(q + 2, __ATOMIC_RELAXED, __HIP_MEMORY_SCOPE_AGENT);
      unsigned a3 = __hip_atomic_load(q + 3, __ATOMIC_RELAXED, __HIP_MEMORY_SCOPE_AGENT);
      if (__all(a0 >= tgt && a1 >= tgt && a2 >= tgt && a3 >= tgt)) break;
      __builtin_amdgcn_s_sleep(2);
    }
    volatile unsigned* tk = tokv;
    if (l == 0) tk[w] = tgt;
    while (tk[0] < tgt || tk[1] < tgt || tk[2] < tgt || tk[3] < tgt) {
    }
    asm volatile("" ::: "memory");
  };
  auto poll1 = [&](unsigned* p, unsigned tgt) {
    while (__hip_atomic_load(p, __ATOMIC_RELAXED, __HIP_MEMORY_SCOPE_AGENT) < tgt)
      __builtin_amdgcn_s_sleep(2);
    asm volatile("" ::: "memory");
  };
  auto chain = [&](const bf16* plane) -> f32x4 {
    f32x4 acc = (f32x4){0.f, 0.f, 0.f, 0.f};
    const char* hp = (const char*)plane;
#pragma unroll 8
    for (int kk = 0; kk < 32; ++kk) {
      int tl = kk * 8 + kq * 2;
      unsigned long long lo = *(const unsigned long long*)(hp + tl * 128 + r16 * 8);
      unsigned long long hi = *(const unsigned long long*)(hp + tl * 128 + 128 + r16 * 8);
      union { struct { unsigned long long a, b; } u; bf16x8 v; } A;
      A.u.a = lo;
      A.u.b = hi;
      bf16x8 Bf = *(const bf16x8*)&wlds[w][r16 * 1024 + (((kk * 4 + kq) ^ (r16 & 7)) << 3)];
      acc = __builtin_amdgcn_mfma_f32_16x16x32_bf16(A.v, Bf, acc, 0, 0, 0);
    }
    return acc;
  };

  if (typ == 1) {
    const float bsv = bsum1[gcol];
    unsigned* const myflag = fB + widx;
    unsigned* const partner = fL1 + widx;
    for (int t = 0; t < T; ++t) {
      if (t >= RING) poll1(partner, (unsigned)(t - RING + 1));
      pollq(fL0, (unsigned)(t + 1));
      f32x4 acc = chain(hs0t + (size_t)t * 16384);
      for (int r = 0; r < 4; ++r) acc[r] += bsv;
      float* dst = gx1 + (size_t)(t & (RING - 1)) * 65536 + widx * 256 + r16 * 16 + kq * 4;
      asm volatile("global_store_dwordx4 %0, %1, off sc0 sc1" ::"v"(dst), "v"(acc) : "memory");
      asm volatile("s_waitcnt vmcnt(0)" ::: "memory");
      if (l == 0)
        __hip_atomic_store(myflag, (unsigned)(t + 1), __ATOMIC_RELAXED, __HIP_MEMORY_SCOPE_AGENT);
    }
    return;
  }

  float cst[4] = {0.f, 0.f, 0.f, 0.f};
  unsigned* const myflag = (typ == 0) ? (fL0 + widx) : (fL1 + widx);
  unsigned* const bpartner = fB + widx;
  bf16* const houts = (typ == 0) ? hs0t : hs1t;

  for (int t = 0; t < T; ++t) {
    float gxv[4];
    if (typ == 0) {
      for (int r = 0; r < 4; ++r)
        gxv[r] = gx[(size_t)(t * 16 + kq * 4 + r) * 4096 + gcol];
    }
    if (typ == 0) {
      if (t > 0) pollq(fL0, (unsigned)t);
    } else {
      poll1(bpartner, (unsigned)(t + 1));
      if (t > 0) pollq(fL1, (unsigned)t);
    }
    f32x4 acc = (f32x4){0.f, 0.f, 0.f, 0.f};
    if (t > 0) acc = chain(houts + (size_t)(t - 1) * 16384);
    if (typ == 0) {
      for (int r = 0; r < 4; ++r) acc[r] += gxv[r];
    } else {
      const float* gp = gx1 + (size_t)(t & (RING - 1)) * 65536 + widx * 256 + r16 * 16 + kq * 4;
      f32x4 g1;
      asm volatile("global_load_dwordx4 %0, %1, off sc0 sc1\ns_waitcnt vmcnt(0)"
                   : "=v"(g1) : "v"(gp) : "memory");
      for (int r = 0; r < 4; ++r) acc[r] += g1[r];
    }
    float hv[4];
    for (int r = 0; r < 4; ++r) {
      float own = acc[r];
      float p4 = __shfl_xor(own, 4, 64);
      float ev = b0s ? p4 : own;
      float ov = b0s ? own : p4;
      float ev8 = __shfl_xor(ev, 8, 64);
      float ov8 = __shfl_xor(ov, 8, 64);
      float xi = b1s ? ev8 : ev;
      float xf = b1s ? ov8 : ov;
      float xg = b1s ? ev : ev8;
      float xo = b1s ? ov : ov8;
      float ig = 1.f / (1.f + __expf(-xi));
      float fg = 1.f / (1.f + __expf(-xf));
      float eg = __expf(2.f * xg);
      float gv = 1.f - 2.f / (eg + 1.f);
      float og = 1.f / (1.f + __expf(-xo));
      cst[r] = fg * cst[r] + ig * gv;
      float ec = __expf(2.f * cst[r]);
      float th = 1.f - 2.f / (ec + 1.f);
      hv[r] = og * th;
    }
    if (r16 < 4) {
      volatile unsigned short* hbp = hb[w];
      for (int r = 0; r < 4; ++r) {
        bf16 hbv = (bf16)hv[r];
        hbp[(kq * 4 + r) * 4 + r16] = __builtin_bit_cast(unsigned short, hbv);
      }
    }
    unsigned long long rowv = 0;
    if (l < 16) rowv = *(volatile unsigned long long*)&hb[w][l * 4];
    if (l < 16) {
      char* dst = (char*)houts + (size_t)t * 32768 + widx * 128 + l * 8;
      asm volatile("global_store_dwordx2 %0, %1, off sc0 sc1" ::"v"(dst), "v"(rowv) : "memory");
    }
    asm volatile("s_waitcnt vmcnt(0)" ::: "memory");
    if (l == 0)
      __hip_atomic_store(myflag, (unsigned)(t + 1), __ATOMIC_RELAXED, __HIP_MEMORY_SCOPE_AGENT);
    if (typ == 2 && l < 16) {  // projection mirror: off critical path, plain store
      *(unsigned long long*)((char*)hs1rm + ((size_t)(t * 16 + l) * 1024 + colbase) * 2) = rowv;
    }
  }
}

extern "C" void kernel_launch(void* const* d_in, const int* in_sizes, int n_in,
                              void* d_out, int out_size, void* d_ws, size_t ws_size,
                              hipStream_t stream) {
  const int* x = (const int*)d_in[0];
  const float* emb = (const float*)d_in[1];
  const float* Wih0 = (const float*)d_in[2];
  const float* Whh0 = (const float*)d_in[3];
  const float* bih0 = (const float*)d_in[4];
  const float* bhh0 = (const float*)d_in[5];
  const float* Wih1 = (const float*)d_in[6];
  const float* Whh1 = (const float*)d_in[7];
  const float* bih1 = (const float*)d_in[8];
  const float* bhh1 = (const float*)d_in[9];
  const float* Wout = (const float*)d_in[10];
  const float* bout = (const float*)d_in[11];

  const int T = 512, M = 8192;
  const size_t bfb = (size_t)M * 1024 * 2;              // 16 MiB bf16 plane set
  const size_t out_bytes = (size_t)out_size * 4;        // 1.05 GB
  const size_t woutb_bytes = (size_t)32000 * 1024 * 2;  // 65.5 MB

  char* p = (char*)d_ws;
  bf16* hs1rm = (bf16*)p;         p += bfb;
  float* bsum0 = (float*)p;       p += 4096 * 4;
  float* bsum1 = (float*)p;       p += 4096 * 4;
  unsigned* flags = (unsigned*)p; p += FLAG_WORDS * 4;
  size_t base_need = (size_t)(p - (char*)d_ws);
  const bool fat = ws_size >= base_need + woutb_bytes + 256;
  bf16* woutb = fat ? (bf16*)p : nullptr;

  // d_out scratch (dead until projection writes it):
  float* gx = (float*)d_out;                             // 134 MB @ head
  float* gx1 = (float*)((char*)d_out + (512ull << 20));  // 2 MB ring
  char* tail = (char*)d_out + out_bytes - 2 * bfb;       // 32 MB tail
  bf16* hs0t = (bf16*)tail;
  bf16* hs1t = (bf16*)(tail + bfb);

  init_misc<<<64, 256, 0, stream>>>(bih0, bhh0, bih1, bhh1, bsum0, bsum1, flags);
  gemm_emb<<<2048 + 4000, 256, 0, stream>>>(x, emb, Wih0, bsum0, gx, Wout, woutb);
  lstm_pipe3<<<192, 256, 0, stream>>>(gx, Whh0, Wih1, Whh1, bsum1, hs0t, hs1t, gx1, hs1rm,
                                      flags, T);
  if (fat)
    gemm_proj<true><<<16000, 256, 0, stream>>>(hs1rm, woutb, bout, (float*)d_out);
  else
    gemm_proj<false><<<16000, 256, 0, stream>>>(hs1rm, Wout, bout, (float*)d_out);
}